// Round 1
// baseline (969.222 us; speedup 1.0000x reference)
//
#include <hip/hip_runtime.h>
#include <math.h>

// QANet Context-Query attention, fp32 correctness-first implementation.
// B=32 H=128 C=2048 Q=256.
// Pipeline:
//   k_partc / k_partq : part_c[b,i], part_q[b,j]
//   k_S               : S = (ctx*w_cq)^T @ q + parts + bias     (ws, 67MB)
//   k_rowstats        : rowmax/rowinv  (softmax over Q, q-masked)
//   k_colpart/combine : colmax/colinv  (softmax over C, c-masked)
//   k_T               : t[b,h,j] = sum_i colnorm[i,j]*ctx[b,h,i]  (reads RAW S)
//   k_norm            : S <- rownorm (in place)
//   k_out             : c2q = RN@q^T, q2c = RN@t, writes all 4 outputs

constexpr int kB = 32, kH = 128, kC = 2048, kQ = 256;
constexpr float kNEG = -1e30f;

__global__ __launch_bounds__(256) void k_partc(const float* __restrict__ ctx,
                                               const float* __restrict__ w_c,
                                               float* __restrict__ part_c) {
    int id = blockIdx.x * 256 + threadIdx.x;   // over B*C
    int b = id / kC, i = id % kC;
    float acc = 0.f;
#pragma unroll 8
    for (int h = 0; h < kH; ++h)
        acc += ctx[((size_t)b * kH + h) * kC + i] * w_c[h];
    part_c[id] = acc;
}

__global__ __launch_bounds__(256) void k_partq(const float* __restrict__ q,
                                               const float* __restrict__ w_q,
                                               float* __restrict__ part_q) {
    int id = blockIdx.x * 256 + threadIdx.x;   // over B*Q
    int b = id / kQ, j = id % kQ;
    float acc = 0.f;
#pragma unroll 8
    for (int h = 0; h < kH; ++h)
        acc += q[((size_t)b * kH + h) * kQ + j] * w_q[h];
    part_q[id] = acc;
}

// S tile 32(i) x 64(j), K-chunks of 8 over h. 256 threads = 32 ii x 8 jg.
__global__ __launch_bounds__(256) void k_S(const float* __restrict__ ctx,
                                           const float* __restrict__ q,
                                           const float* __restrict__ w_cq,
                                           const float* __restrict__ part_c,
                                           const float* __restrict__ part_q,
                                           const float* __restrict__ bias,
                                           float* __restrict__ S) {
    int i0 = blockIdx.x * 32;
    int j0 = blockIdx.y * 64;
    int b  = blockIdx.z;
    __shared__ float ct[8][33];
    __shared__ float qt[8][65];
    int t = threadIdx.x;
    int ii = t % 32, jg = t / 32;
    float acc[8] = {0, 0, 0, 0, 0, 0, 0, 0};
    for (int h0 = 0; h0 < kH; h0 += 8) {
        {
            int hh = t / 32, col = t % 32;
            ct[hh][col] = ctx[((size_t)b * kH + h0 + hh) * kC + i0 + col] * w_cq[h0 + hh];
        }
#pragma unroll
        for (int r = 0; r < 2; ++r) {
            int idx = r * 256 + t;
            int hh = idx / 64, col = idx % 64;
            qt[hh][col] = q[((size_t)b * kH + h0 + hh) * kQ + j0 + col];
        }
        __syncthreads();
#pragma unroll
        for (int hh = 0; hh < 8; ++hh) {
            float c = ct[hh][ii];
#pragma unroll
            for (int u = 0; u < 8; ++u)
                acc[u] += c * qt[hh][jg * 8 + u];
        }
        __syncthreads();
    }
    float pc = part_c[b * kC + i0 + ii];
    float bs = bias[0];
#pragma unroll
    for (int u = 0; u < 8; ++u) {
        int j = j0 + jg * 8 + u;
        S[((size_t)b * kC + i0 + ii) * kQ + j] = acc[u] + pc + part_q[b * kQ + j] + bs;
    }
}

// One wave per (b,i) row: max + sum of exp over Q=256 (4 elems/lane).
__global__ __launch_bounds__(256) void k_rowstats(const float* __restrict__ S,
                                                  const int* __restrict__ qmask,
                                                  float* __restrict__ rowmax,
                                                  float* __restrict__ rowinv) {
    int gtid = blockIdx.x * 256 + threadIdx.x;
    int wid = gtid / 64;          // row id over B*C
    int lane = threadIdx.x % 64;
    int b = wid / kC;
    const float* row = S + (size_t)wid * kQ;
    const int* qm = qmask + b * kQ;
    float v[4];
    float m = kNEG;
#pragma unroll
    for (int k = 0; k < 4; ++k) {
        int j = lane + k * 64;
        v[k] = qm[j] ? row[j] : kNEG;
        m = fmaxf(m, v[k]);
    }
    for (int off = 32; off; off >>= 1) m = fmaxf(m, __shfl_xor(m, off));
    float s = 0.f;
#pragma unroll
    for (int k = 0; k < 4; ++k) s += (v[k] > -1e29f) ? __expf(v[k] - m) : 0.f;
    for (int off = 32; off; off >>= 1) s += __shfl_xor(s, off);
    if (lane == 0) { rowmax[wid] = m; rowinv[wid] = 1.f / s; }
}

// Column-softmax partial stats: 8 chunks of 256 i each; 256 threads = Q.
__global__ __launch_bounds__(256) void k_colpart(const float* __restrict__ S,
                                                 const int* __restrict__ cmask,
                                                 float* __restrict__ pm,
                                                 float* __restrict__ ps) {
    int chunk = blockIdx.x, b = blockIdx.y;
    int j = threadIdx.x;
    const int* cm = cmask + b * kC;
    float m = kNEG, s = 0.f;
    int ibeg = chunk * 256;
    for (int i = ibeg; i < ibeg + 256; ++i) {
        if (!cm[i]) continue;
        float v = S[((size_t)b * kC + i) * kQ + j];
        if (v > m) { s = s * __expf(m - v) + 1.f; m = v; }
        else       { s += __expf(v - m); }
    }
    pm[(b * 8 + chunk) * kQ + j] = m;
    ps[(b * 8 + chunk) * kQ + j] = s;
}

__global__ __launch_bounds__(256) void k_colcombine(const float* __restrict__ pm,
                                                    const float* __restrict__ ps,
                                                    float* __restrict__ colmax,
                                                    float* __restrict__ colinv) {
    int id = blockIdx.x * 256 + threadIdx.x;   // over B*Q
    int b = id / kQ, j = id % kQ;
    float m = kNEG;
#pragma unroll
    for (int c = 0; c < 8; ++c) m = fmaxf(m, pm[(b * 8 + c) * kQ + j]);
    float s = 0.f;
#pragma unroll
    for (int c = 0; c < 8; ++c) {
        float pmv = pm[(b * 8 + c) * kQ + j];
        float psv = ps[(b * 8 + c) * kQ + j];
        if (pmv > -1e29f) s += psv * __expf(pmv - m);
    }
    colmax[id] = m;
    colinv[id] = 1.f / s;
}

// t[b,h,j] = (sum_i cmask[i]*exp(S[i,j]-colmax[j]) * ctx[b,h,i]) * colinv[j]
// Block: (ht 32 h's, jt 64 j's, b). 256 thr = 64 jj x 4 hg (8 h each).
__global__ __launch_bounds__(256) void k_T(const float* __restrict__ S,
                                           const float* __restrict__ ctx,
                                           const int* __restrict__ cmask,
                                           const float* __restrict__ colmax,
                                           const float* __restrict__ colinv,
                                           float* __restrict__ T) {
    int ht = blockIdx.x, jt = blockIdx.y, b = blockIdx.z;
    int h0 = ht * 32, j0 = jt * 64;
    __shared__ float et[32][65];
    __shared__ float ctile[32][33];
    int t = threadIdx.x;
    int jj = t % 64, hg = t / 64;
    float acc[8] = {0, 0, 0, 0, 0, 0, 0, 0};
    for (int i0 = 0; i0 < kC; i0 += 32) {
#pragma unroll
        for (int r = 0; r < 8; ++r) {
            int idx = r * 256 + t;
            int ri = idx / 64, cj = idx % 64;
            float v = S[((size_t)b * kC + i0 + ri) * kQ + j0 + cj];
            et[ri][cj] = cmask[b * kC + i0 + ri]
                             ? __expf(v - colmax[b * kQ + j0 + cj]) : 0.f;
        }
#pragma unroll
        for (int r = 0; r < 4; ++r) {
            int idx = r * 256 + t;
            int hh = idx / 32, ii = idx % 32;
            ctile[hh][ii] = ctx[((size_t)b * kH + h0 + hh) * kC + i0 + ii];
        }
        __syncthreads();
#pragma unroll
        for (int ii = 0; ii < 32; ++ii) {
            float e = et[ii][jj];
#pragma unroll
            for (int u = 0; u < 8; ++u)
                acc[u] += e * ctile[hg * 8 + u][ii];
        }
        __syncthreads();
    }
    float ci = colinv[b * kQ + j0 + jj];
#pragma unroll
    for (int u = 0; u < 8; ++u)
        T[((size_t)b * kH + h0 + hg * 8 + u) * kQ + j0 + jj] = acc[u] * ci;
}

// In-place: S <- row-normalized softmax. One block per (b,i) row (256 = Q).
__global__ __launch_bounds__(256) void k_norm(float* __restrict__ S,
                                              const int* __restrict__ qmask,
                                              const float* __restrict__ rowmax,
                                              const float* __restrict__ rowinv) {
    size_t id = (size_t)blockIdx.x * 256 + threadIdx.x;
    int j = (int)(id % kQ);
    int bi = (int)(id / kQ);
    int b = bi / kC;
    float v = S[id];
    S[id] = qmask[b * kQ + j] ? __expf(v - rowmax[bi]) * rowinv[bi] : 0.f;
}

// c2q = RN @ q^T, q2c = RN @ t; write all 4 outputs.
// Block: (it 32 i's, ht 64 h's, b). 256 thr = 32 ii x 8 hg (8 h each).
__global__ __launch_bounds__(256) void k_out(const float* __restrict__ RN,
                                             const float* __restrict__ q,
                                             const float* __restrict__ T,
                                             const float* __restrict__ ctx,
                                             float* __restrict__ out) {
    int it = blockIdx.x, ht = blockIdx.y, b = blockIdx.z;
    int i0 = it * 32, h0 = ht * 64;
    __shared__ float rt[32][65];
    __shared__ float qt[64][65];
    __shared__ float tt[64][65];
    int t = threadIdx.x;
    int ii = t % 32, hg = t / 32;
    float ac[8] = {0, 0, 0, 0, 0, 0, 0, 0};
    float aq[8] = {0, 0, 0, 0, 0, 0, 0, 0};
    for (int j0 = 0; j0 < kQ; j0 += 64) {
#pragma unroll
        for (int r = 0; r < 8; ++r) {
            int idx = r * 256 + t;
            int ri = idx / 64, cj = idx % 64;
            rt[ri][cj] = RN[((size_t)b * kC + i0 + ri) * kQ + j0 + cj];
        }
#pragma unroll
        for (int r = 0; r < 16; ++r) {
            int idx = r * 256 + t;
            int hh = idx / 64, cj = idx % 64;
            qt[hh][cj] = q[((size_t)b * kH + h0 + hh) * kQ + j0 + cj];
            tt[hh][cj] = T[((size_t)b * kH + h0 + hh) * kQ + j0 + cj];
        }
        __syncthreads();
#pragma unroll
        for (int jj = 0; jj < 64; ++jj) {
            float r = rt[ii][jj];
#pragma unroll
            for (int u = 0; u < 8; ++u) {
                ac[u] += r * qt[hg * 8 + u][jj];
                aq[u] += r * tt[hg * 8 + u][jj];
            }
        }
        __syncthreads();
    }
    const size_t N = (size_t)kB * kH * kC;
#pragma unroll
    for (int u = 0; u < 8; ++u) {
        int h = h0 + hg * 8 + u;
        size_t base = ((size_t)b * kH + h) * kC + i0 + ii;
        float cv = ctx[base];
        out[base]         = cv;
        out[N + base]     = ac[u];
        out[2 * N + base] = cv * ac[u];
        out[3 * N + base] = cv * aq[u];
    }
}

extern "C" void kernel_launch(void* const* d_in, const int* in_sizes, int n_in,
                              void* d_out, int out_size, void* d_ws, size_t ws_size,
                              hipStream_t stream) {
    const float* ctx   = (const float*)d_in[0];
    const float* q     = (const float*)d_in[1];
    const int*   cmask = (const int*)d_in[2];
    const int*   qmask = (const int*)d_in[3];
    const float* w_c   = (const float*)d_in[4];
    const float* w_q   = (const float*)d_in[5];
    const float* w_cq  = (const float*)d_in[6];
    const float* bias  = (const float*)d_in[7];
    float* out = (float*)d_out;

    float* ws = (float*)d_ws;
    float* S      = ws;                             // B*C*Q = 16,777,216
    float* T      = S + (size_t)kB * kC * kQ;       // B*H*Q = 1,048,576
    float* part_c = T + (size_t)kB * kH * kQ;       // B*C
    float* part_q = part_c + kB * kC;               // B*Q
    float* rowmax = part_q + kB * kQ;               // B*C
    float* rowinv = rowmax + kB * kC;               // B*C
    float* colmax = rowinv + kB * kC;               // B*Q
    float* colinv = colmax + kB * kQ;               // B*Q
    float* pm     = colinv + kB * kQ;               // B*8*Q
    float* ps     = pm + kB * 8 * kQ;               // B*8*Q
    size_t need = (size_t)(ps + kB * 8 * kQ - ws) * sizeof(float);
    if (ws_size < need) return;  // ~70 MB required; bail loudly (outputs stay poisoned)

    k_partc<<<kB * kC / 256, 256, 0, stream>>>(ctx, w_c, part_c);
    k_partq<<<kB * kQ / 256, 256, 0, stream>>>(q, w_q, part_q);
    k_S<<<dim3(kC / 32, kQ / 64, kB), 256, 0, stream>>>(ctx, q, w_cq, part_c, part_q, bias, S);
    k_rowstats<<<kB * kC / 4, 256, 0, stream>>>(S, qmask, rowmax, rowinv);
    k_colpart<<<dim3(8, kB), 256, 0, stream>>>(S, cmask, pm, ps);
    k_colcombine<<<kB * kQ / 256, 256, 0, stream>>>(pm, ps, colmax, colinv);
    k_T<<<dim3(kH / 32, kQ / 64, kB), 256, 0, stream>>>(S, ctx, cmask, colmax, colinv, T);
    k_norm<<<kB * kC * kQ / 256, 256, 0, stream>>>(S, qmask, rowmax, rowinv);
    k_out<<<dim3(kC / 32, kH / 64, kB), 256, 0, stream>>>(S, q, T, ctx, out);
}

// Round 2
// 558.019 us; speedup vs baseline: 1.7369x; 1.7369x over previous
//
#include <hip/hip_runtime.h>
#include <math.h>

// QANet Context-Query attention, fp32. B=32 H=128 C=2048 Q=256.
// R1: k_T restructured as split-K partial GEMM (exp computed once per S elem,
//     register-tiled 8hx4j per thread, float4 LDS reads), partials in d_out
//     scratch, reduced by k_Tred. k_colpart chunks 8->32. k_S float4 qt reads.

constexpr int kB = 32, kH = 128, kC = 2048, kQ = 256;
constexpr int kColChunks = 32;           // col-softmax partial chunks (64 i each)
constexpr float kNEG = -1e30f;

__global__ __launch_bounds__(256) void k_partc(const float* __restrict__ ctx,
                                               const float* __restrict__ w_c,
                                               float* __restrict__ part_c) {
    int id = blockIdx.x * 256 + threadIdx.x;   // over B*C
    int b = id / kC, i = id % kC;
    float acc = 0.f;
#pragma unroll 8
    for (int h = 0; h < kH; ++h)
        acc += ctx[((size_t)b * kH + h) * kC + i] * w_c[h];
    part_c[id] = acc;
}

__global__ __launch_bounds__(256) void k_partq(const float* __restrict__ q,
                                               const float* __restrict__ w_q,
                                               float* __restrict__ part_q) {
    int id = blockIdx.x * 256 + threadIdx.x;   // over B*Q
    int b = id / kQ, j = id % kQ;
    float acc = 0.f;
#pragma unroll 8
    for (int h = 0; h < kH; ++h)
        acc += q[((size_t)b * kH + h) * kQ + j] * w_q[h];
    part_q[id] = acc;
}

// S tile 32(i) x 64(j), K-chunks of 8 over h. 256 threads = 32 ii x 8 jg.
__global__ __launch_bounds__(256) void k_S(const float* __restrict__ ctx,
                                           const float* __restrict__ q,
                                           const float* __restrict__ w_cq,
                                           const float* __restrict__ part_c,
                                           const float* __restrict__ part_q,
                                           const float* __restrict__ bias,
                                           float* __restrict__ S) {
    int i0 = blockIdx.x * 32;
    int j0 = blockIdx.y * 64;
    int b  = blockIdx.z;
    __shared__ float ct[8][33];
    __shared__ float qt[8][68];              // 68: rows 16B-aligned for float4
    int t = threadIdx.x;
    int ii = t % 32, jg = t / 32;
    float acc[8] = {0, 0, 0, 0, 0, 0, 0, 0};
    for (int h0 = 0; h0 < kH; h0 += 8) {
        {
            int hh = t / 32, col = t % 32;
            ct[hh][col] = ctx[((size_t)b * kH + h0 + hh) * kC + i0 + col] * w_cq[h0 + hh];
        }
#pragma unroll
        for (int r = 0; r < 2; ++r) {
            int idx = r * 256 + t;
            int hh = idx / 64, col = idx % 64;
            qt[hh][col] = q[((size_t)b * kH + h0 + hh) * kQ + j0 + col];
        }
        __syncthreads();
#pragma unroll
        for (int hh = 0; hh < 8; ++hh) {
            float c = ct[hh][ii];
            float4 q0 = *(const float4*)&qt[hh][jg * 8];
            float4 q1 = *(const float4*)&qt[hh][jg * 8 + 4];
            acc[0] += c * q0.x; acc[1] += c * q0.y;
            acc[2] += c * q0.z; acc[3] += c * q0.w;
            acc[4] += c * q1.x; acc[5] += c * q1.y;
            acc[6] += c * q1.z; acc[7] += c * q1.w;
        }
        __syncthreads();
    }
    float pc = part_c[b * kC + i0 + ii];
    float bs = bias[0];
#pragma unroll
    for (int u = 0; u < 8; ++u) {
        int j = j0 + jg * 8 + u;
        S[((size_t)b * kC + i0 + ii) * kQ + j] = acc[u] + pc + part_q[b * kQ + j] + bs;
    }
}

// One wave per (b,i) row: max + sum of exp over Q=256 (4 elems/lane).
__global__ __launch_bounds__(256) void k_rowstats(const float* __restrict__ S,
                                                  const int* __restrict__ qmask,
                                                  float* __restrict__ rowmax,
                                                  float* __restrict__ rowinv) {
    int gtid = blockIdx.x * 256 + threadIdx.x;
    int wid = gtid / 64;          // row id over B*C
    int lane = threadIdx.x % 64;
    int b = wid / kC;
    const float* row = S + (size_t)wid * kQ;
    const int* qm = qmask + b * kQ;
    float v[4];
    float m = kNEG;
#pragma unroll
    for (int k = 0; k < 4; ++k) {
        int j = lane + k * 64;
        v[k] = qm[j] ? row[j] : kNEG;
        m = fmaxf(m, v[k]);
    }
    for (int off = 32; off; off >>= 1) m = fmaxf(m, __shfl_xor(m, off));
    float s = 0.f;
#pragma unroll
    for (int k = 0; k < 4; ++k) s += (v[k] > -1e29f) ? __expf(v[k] - m) : 0.f;
    for (int off = 32; off; off >>= 1) s += __shfl_xor(s, off);
    if (lane == 0) { rowmax[wid] = m; rowinv[wid] = 1.f / s; }
}

// Column-softmax partial stats: kColChunks chunks of kC/kColChunks i; 256 thr = Q.
__global__ __launch_bounds__(256) void k_colpart(const float* __restrict__ S,
                                                 const int* __restrict__ cmask,
                                                 float* __restrict__ pm,
                                                 float* __restrict__ ps) {
    int chunk = blockIdx.x, b = blockIdx.y;
    int j = threadIdx.x;
    const int* cm = cmask + b * kC;
    float m = kNEG, s = 0.f;
    int ibeg = chunk * (kC / kColChunks);
    for (int i = ibeg; i < ibeg + kC / kColChunks; ++i) {
        if (!cm[i]) continue;
        float v = S[((size_t)b * kC + i) * kQ + j];
        if (v > m) { s = s * __expf(m - v) + 1.f; m = v; }
        else       { s += __expf(v - m); }
    }
    pm[(b * kColChunks + chunk) * kQ + j] = m;
    ps[(b * kColChunks + chunk) * kQ + j] = s;
}

__global__ __launch_bounds__(256) void k_colcombine(const float* __restrict__ pm,
                                                    const float* __restrict__ ps,
                                                    float* __restrict__ colmax,
                                                    float* __restrict__ colinv) {
    int id = blockIdx.x * 256 + threadIdx.x;   // over B*Q
    int b = id / kQ, j = id % kQ;
    float m = kNEG;
#pragma unroll
    for (int c = 0; c < kColChunks; ++c) m = fmaxf(m, pm[(b * kColChunks + c) * kQ + j]);
    float s = 0.f;
#pragma unroll
    for (int c = 0; c < kColChunks; ++c) {
        float pmv = pm[(b * kColChunks + c) * kQ + j];
        float psv = ps[(b * kColChunks + c) * kQ + j];
        if (pmv > -1e29f) s += psv * __expf(pmv - m);
    }
    colmax[id] = m;
    colinv[id] = 1.f / s;
}

// Tpart[chunk][b][h][j] = sum_{i in chunk} cmask[i]*exp(S[i,j]-colmax[j])*ctx[h,i]
// Grid (8 chunks of 256 i, 4 j-tiles of 64, B). 256 thr: 16 jgrp(4j) x 16 hgrp(8h).
// Each S element read+exp'd exactly once. FMA-bound: 3 b128 LDS reads / 32 FMA.
__global__ __launch_bounds__(256) void k_T2(const float* __restrict__ S,
                                            const float* __restrict__ ctx,
                                            const int* __restrict__ cmask,
                                            const float* __restrict__ colmax,
                                            float* __restrict__ Tpart) {
    int chunk = blockIdx.x, jt = blockIdx.y, b = blockIdx.z;
    int j0 = jt * 64;
    __shared__ float et[32][68];     // [i][j], 64+4 pad (rows 16B aligned)
    __shared__ float ctT[32][132];   // [i][h], 128+4 pad (rows 16B aligned)
    __shared__ int   smc[256];       // cmask for this chunk's i-range
    int t = threadIdx.x;
    int jj = (t % 16) * 4;
    int hh = (t / 16) * 8;
    float cmj = colmax[b * kQ + j0 + (t % 64)];
    smc[t] = cmask[b * kC + chunk * 256 + t];
    __syncthreads();
    float acc[8][4] = {};
    for (int it = 0; it < 8; ++it) {
        int i0 = chunk * 256 + it * 32;
        {   // S tile -> exp -> et
            int r = t / 64, c = t % 64;
#pragma unroll
            for (int p = 0; p < 8; ++p) {
                int il = it * 32 + p * 4 + r;
                float v = S[((size_t)b * kC + chunk * 256 + il) * kQ + j0 + c];
                et[p * 4 + r][c] = smc[il] ? __expf(v - cmj) : 0.f;
            }
        }
        {   // ctx tile transposed -> ctT
            int hr = t / 32, ic = t % 32;
#pragma unroll
            for (int p = 0; p < 16; ++p) {
                int h = p * 8 + hr;
                ctT[ic][h] = ctx[((size_t)b * kH + h) * kC + i0 + ic];
            }
        }
        __syncthreads();
#pragma unroll 8
        for (int i = 0; i < 32; ++i) {
            float4 e  = *(const float4*)&et[i][jj];
            float4 c0 = *(const float4*)&ctT[i][hh];
            float4 c1 = *(const float4*)&ctT[i][hh + 4];
            float cv[8] = {c0.x, c0.y, c0.z, c0.w, c1.x, c1.y, c1.z, c1.w};
            float ev[4] = {e.x, e.y, e.z, e.w};
#pragma unroll
            for (int u = 0; u < 8; ++u)
#pragma unroll
                for (int v = 0; v < 4; ++v)
                    acc[u][v] += cv[u] * ev[v];
        }
        __syncthreads();
    }
    const size_t M = (size_t)kB * kH * kQ;
#pragma unroll
    for (int u = 0; u < 8; ++u) {
        size_t base = (size_t)chunk * M + ((size_t)b * kH + hh + u) * kQ + j0 + jj;
        *(float4*)&Tpart[base] = make_float4(acc[u][0], acc[u][1], acc[u][2], acc[u][3]);
    }
}

// T[b,h,j] = colinv[b,j] * sum_chunk Tpart[chunk][b,h,j]
__global__ __launch_bounds__(256) void k_Tred(const float* __restrict__ Tpart,
                                              const float* __restrict__ colinv,
                                              float* __restrict__ T) {
    size_t id = (size_t)blockIdx.x * 256 + threadIdx.x;   // over B*H*Q
    const size_t M = (size_t)kB * kH * kQ;
    int j = (int)(id % kQ);
    int b = (int)(id / ((size_t)kH * kQ));
    float s = 0.f;
#pragma unroll
    for (int c = 0; c < 8; ++c) s += Tpart[c * M + id];
    T[id] = s * colinv[b * kQ + j];
}

// In-place: S <- row-normalized softmax.
__global__ __launch_bounds__(256) void k_norm(float* __restrict__ S,
                                              const int* __restrict__ qmask,
                                              const float* __restrict__ rowmax,
                                              const float* __restrict__ rowinv) {
    size_t id = (size_t)blockIdx.x * 256 + threadIdx.x;
    int j = (int)(id % kQ);
    int bi = (int)(id / kQ);
    int b = bi / kC;
    float v = S[id];
    S[id] = qmask[b * kQ + j] ? __expf(v - rowmax[bi]) * rowinv[bi] : 0.f;
}

// c2q = RN @ q^T, q2c = RN @ t; write all 4 outputs.
__global__ __launch_bounds__(256) void k_out(const float* __restrict__ RN,
                                             const float* __restrict__ q,
                                             const float* __restrict__ T,
                                             const float* __restrict__ ctx,
                                             float* __restrict__ out) {
    int it = blockIdx.x, ht = blockIdx.y, b = blockIdx.z;
    int i0 = it * 32, h0 = ht * 64;
    __shared__ float rt[32][65];
    __shared__ float qt[64][65];
    __shared__ float tt[64][65];
    int t = threadIdx.x;
    int ii = t % 32, hg = t / 32;
    float ac[8] = {0, 0, 0, 0, 0, 0, 0, 0};
    float aq[8] = {0, 0, 0, 0, 0, 0, 0, 0};
    for (int j0 = 0; j0 < kQ; j0 += 64) {
#pragma unroll
        for (int r = 0; r < 8; ++r) {
            int idx = r * 256 + t;
            int ri = idx / 64, cj = idx % 64;
            rt[ri][cj] = RN[((size_t)b * kC + i0 + ri) * kQ + j0 + cj];
        }
#pragma unroll
        for (int r = 0; r < 16; ++r) {
            int idx = r * 256 + t;
            int hh = idx / 64, cj = idx % 64;
            qt[hh][cj] = q[((size_t)b * kH + h0 + hh) * kQ + j0 + cj];
            tt[hh][cj] = T[((size_t)b * kH + h0 + hh) * kQ + j0 + cj];
        }
        __syncthreads();
#pragma unroll
        for (int jj = 0; jj < 64; ++jj) {
            float r = rt[ii][jj];
#pragma unroll
            for (int u = 0; u < 8; ++u) {
                ac[u] += r * qt[hg * 8 + u][jj];
                aq[u] += r * tt[hg * 8 + u][jj];
            }
        }
        __syncthreads();
    }
    const size_t N = (size_t)kB * kH * kC;
#pragma unroll
    for (int u = 0; u < 8; ++u) {
        int h = h0 + hg * 8 + u;
        size_t base = ((size_t)b * kH + h) * kC + i0 + ii;
        float cv = ctx[base];
        out[base]         = cv;
        out[N + base]     = ac[u];
        out[2 * N + base] = cv * ac[u];
        out[3 * N + base] = cv * aq[u];
    }
}

extern "C" void kernel_launch(void* const* d_in, const int* in_sizes, int n_in,
                              void* d_out, int out_size, void* d_ws, size_t ws_size,
                              hipStream_t stream) {
    const float* ctx   = (const float*)d_in[0];
    const float* q     = (const float*)d_in[1];
    const int*   cmask = (const int*)d_in[2];
    const int*   qmask = (const int*)d_in[3];
    const float* w_c   = (const float*)d_in[4];
    const float* w_q   = (const float*)d_in[5];
    const float* w_cq  = (const float*)d_in[6];
    const float* bias  = (const float*)d_in[7];
    float* out = (float*)d_out;

    float* ws = (float*)d_ws;
    float* S      = ws;                             // B*C*Q = 16,777,216
    float* T      = S + (size_t)kB * kC * kQ;       // B*H*Q = 1,048,576
    float* part_c = T + (size_t)kB * kH * kQ;       // B*C
    float* part_q = part_c + kB * kC;               // B*Q
    float* rowmax = part_q + kB * kQ;               // B*C
    float* rowinv = rowmax + kB * kC;               // B*C
    float* colmax = rowinv + kB * kC;               // B*Q
    float* colinv = colmax + kB * kQ;               // B*Q
    float* pm     = colinv + kB * kQ;               // B*kColChunks*Q
    float* ps     = pm + kB * kColChunks * kQ;      // B*kColChunks*Q
    size_t need = (size_t)(ps + kB * kColChunks * kQ - ws) * sizeof(float);
    if (ws_size < need) return;

    // Tpart (8 * B*H*Q floats = 33.5 MB) lives in d_out; k_out fully
    // overwrites d_out afterwards, so this is safe scratch.
    float* Tpart = out;

    k_partc<<<kB * kC / 256, 256, 0, stream>>>(ctx, w_c, part_c);
    k_partq<<<kB * kQ / 256, 256, 0, stream>>>(q, w_q, part_q);
    k_S<<<dim3(kC / 32, kQ / 64, kB), 256, 0, stream>>>(ctx, q, w_cq, part_c, part_q, bias, S);
    k_rowstats<<<kB * kC / 4, 256, 0, stream>>>(S, qmask, rowmax, rowinv);
    k_colpart<<<dim3(kColChunks, kB), 256, 0, stream>>>(S, cmask, pm, ps);
    k_colcombine<<<kB * kQ / 256, 256, 0, stream>>>(pm, ps, colmax, colinv);
    k_T2<<<dim3(8, kQ / 64, kB), 256, 0, stream>>>(S, ctx, cmask, colmax, Tpart);
    k_Tred<<<kB * kH * kQ / 256, 256, 0, stream>>>(Tpart, colinv, T);
    k_norm<<<kB * kC * kQ / 256, 256, 0, stream>>>(S, qmask, rowmax, rowinv);
    k_out<<<dim3(kC / 32, kH / 64, kB), 256, 0, stream>>>(S, q, T, ctx, out);
}

// Round 4
// 291.048 us; speedup vs baseline: 3.3301x; 1.9173x over previous
//
#include <hip/hip_runtime.h>
#include <hip/hip_bf16.h>
#include <math.h>

// QANet Context-Query attention. B=32 H=128 C=2048 Q=256.
// R2: k_out -> bf16 MFMA (16x16x32), k_norm fused into k_out's A-staging
//     (raw S -> masked rownorm -> bf16), k_Tred emits bf16 T.
// R3: identical resubmit (R2 bench died on infra: UnresponsiveContainer).

constexpr int kB = 32, kH = 128, kC = 2048, kQ = 256;
constexpr int kColChunks = 32;
constexpr float kNEG = -1e30f;

typedef short bf16x8 __attribute__((ext_vector_type(8)));
typedef float f32x4 __attribute__((ext_vector_type(4)));

static __device__ __forceinline__ unsigned short f2bf(float f) {
    __hip_bfloat16 h = __float2bfloat16(f);
    return __builtin_bit_cast(unsigned short, h);
}

__global__ __launch_bounds__(256) void k_partc(const float* __restrict__ ctx,
                                               const float* __restrict__ w_c,
                                               float* __restrict__ part_c) {
    int id = blockIdx.x * 256 + threadIdx.x;   // over B*C
    int b = id / kC, i = id % kC;
    float acc = 0.f;
#pragma unroll 8
    for (int h = 0; h < kH; ++h)
        acc += ctx[((size_t)b * kH + h) * kC + i] * w_c[h];
    part_c[id] = acc;
}

__global__ __launch_bounds__(256) void k_partq(const float* __restrict__ q,
                                               const float* __restrict__ w_q,
                                               float* __restrict__ part_q) {
    int id = blockIdx.x * 256 + threadIdx.x;   // over B*Q
    int b = id / kQ, j = id % kQ;
    float acc = 0.f;
#pragma unroll 8
    for (int h = 0; h < kH; ++h)
        acc += q[((size_t)b * kH + h) * kQ + j] * w_q[h];
    part_q[id] = acc;
}

// S tile 32(i) x 64(j), K-chunks of 8 over h. 256 threads = 32 ii x 8 jg.
__global__ __launch_bounds__(256) void k_S(const float* __restrict__ ctx,
                                           const float* __restrict__ q,
                                           const float* __restrict__ w_cq,
                                           const float* __restrict__ part_c,
                                           const float* __restrict__ part_q,
                                           const float* __restrict__ bias,
                                           float* __restrict__ S) {
    int i0 = blockIdx.x * 32;
    int j0 = blockIdx.y * 64;
    int b  = blockIdx.z;
    __shared__ float ct[8][33];
    __shared__ float qt[8][68];
    int t = threadIdx.x;
    int ii = t % 32, jg = t / 32;
    float acc[8] = {0, 0, 0, 0, 0, 0, 0, 0};
    for (int h0 = 0; h0 < kH; h0 += 8) {
        {
            int hh = t / 32, col = t % 32;
            ct[hh][col] = ctx[((size_t)b * kH + h0 + hh) * kC + i0 + col] * w_cq[h0 + hh];
        }
#pragma unroll
        for (int r = 0; r < 2; ++r) {
            int idx = r * 256 + t;
            int hh = idx / 64, col = idx % 64;
            qt[hh][col] = q[((size_t)b * kH + h0 + hh) * kQ + j0 + col];
        }
        __syncthreads();
#pragma unroll
        for (int hh = 0; hh < 8; ++hh) {
            float c = ct[hh][ii];
            float4 q0 = *(const float4*)&qt[hh][jg * 8];
            float4 q1 = *(const float4*)&qt[hh][jg * 8 + 4];
            acc[0] += c * q0.x; acc[1] += c * q0.y;
            acc[2] += c * q0.z; acc[3] += c * q0.w;
            acc[4] += c * q1.x; acc[5] += c * q1.y;
            acc[6] += c * q1.z; acc[7] += c * q1.w;
        }
        __syncthreads();
    }
    float pc = part_c[b * kC + i0 + ii];
    float bs = bias[0];
#pragma unroll
    for (int u = 0; u < 8; ++u) {
        int j = j0 + jg * 8 + u;
        S[((size_t)b * kC + i0 + ii) * kQ + j] = acc[u] + pc + part_q[b * kQ + j] + bs;
    }
}

// One wave per (b,i) row: max + sum of exp over Q=256 (4 elems/lane).
__global__ __launch_bounds__(256) void k_rowstats(const float* __restrict__ S,
                                                  const int* __restrict__ qmask,
                                                  float* __restrict__ rowmax,
                                                  float* __restrict__ rowinv) {
    int gtid = blockIdx.x * 256 + threadIdx.x;
    int wid = gtid / 64;          // row id over B*C
    int lane = threadIdx.x % 64;
    int b = wid / kC;
    const float* row = S + (size_t)wid * kQ;
    const int* qm = qmask + b * kQ;
    float v[4];
    float m = kNEG;
#pragma unroll
    for (int k = 0; k < 4; ++k) {
        int j = lane + k * 64;
        v[k] = qm[j] ? row[j] : kNEG;
        m = fmaxf(m, v[k]);
    }
    for (int off = 32; off; off >>= 1) m = fmaxf(m, __shfl_xor(m, off));
    float s = 0.f;
#pragma unroll
    for (int k = 0; k < 4; ++k) s += (v[k] > -1e29f) ? __expf(v[k] - m) : 0.f;
    for (int off = 32; off; off >>= 1) s += __shfl_xor(s, off);
    if (lane == 0) { rowmax[wid] = m; rowinv[wid] = 1.f / s; }
}

// Column-softmax partial stats: kColChunks chunks; 256 thr = Q.
__global__ __launch_bounds__(256) void k_colpart(const float* __restrict__ S,
                                                 const int* __restrict__ cmask,
                                                 float* __restrict__ pm,
                                                 float* __restrict__ ps) {
    int chunk = blockIdx.x, b = blockIdx.y;
    int j = threadIdx.x;
    const int* cm = cmask + b * kC;
    float m = kNEG, s = 0.f;
    int ibeg = chunk * (kC / kColChunks);
    for (int i = ibeg; i < ibeg + kC / kColChunks; ++i) {
        if (!cm[i]) continue;
        float v = S[((size_t)b * kC + i) * kQ + j];
        if (v > m) { s = s * __expf(m - v) + 1.f; m = v; }
        else       { s += __expf(v - m); }
    }
    pm[(b * kColChunks + chunk) * kQ + j] = m;
    ps[(b * kColChunks + chunk) * kQ + j] = s;
}

__global__ __launch_bounds__(256) void k_colcombine(const float* __restrict__ pm,
                                                    const float* __restrict__ ps,
                                                    float* __restrict__ colmax,
                                                    float* __restrict__ colinv) {
    int id = blockIdx.x * 256 + threadIdx.x;   // over B*Q
    int b = id / kQ, j = id % kQ;
    float m = kNEG;
#pragma unroll
    for (int c = 0; c < kColChunks; ++c) m = fmaxf(m, pm[(b * kColChunks + c) * kQ + j]);
    float s = 0.f;
#pragma unroll
    for (int c = 0; c < kColChunks; ++c) {
        float pmv = pm[(b * kColChunks + c) * kQ + j];
        float psv = ps[(b * kColChunks + c) * kQ + j];
        if (pmv > -1e29f) s += psv * __expf(pmv - m);
    }
    colmax[id] = m;
    colinv[id] = 1.f / s;
}

// Tpart[chunk][b][h][j] = sum_{i in chunk} cmask[i]*exp(S[i,j]-colmax[j])*ctx[h,i]
__global__ __launch_bounds__(256) void k_T2(const float* __restrict__ S,
                                            const float* __restrict__ ctx,
                                            const int* __restrict__ cmask,
                                            const float* __restrict__ colmax,
                                            float* __restrict__ Tpart) {
    int chunk = blockIdx.x, jt = blockIdx.y, b = blockIdx.z;
    int j0 = jt * 64;
    __shared__ float et[32][68];
    __shared__ float ctT[32][132];
    __shared__ int   smc[256];
    int t = threadIdx.x;
    int jj = (t % 16) * 4;
    int hh = (t / 16) * 8;
    float cmj = colmax[b * kQ + j0 + (t % 64)];
    smc[t] = cmask[b * kC + chunk * 256 + t];
    __syncthreads();
    float acc[8][4] = {};
    for (int it = 0; it < 8; ++it) {
        int i0 = chunk * 256 + it * 32;
        {
            int r = t / 64, c = t % 64;
#pragma unroll
            for (int p = 0; p < 8; ++p) {
                int il = it * 32 + p * 4 + r;
                float v = S[((size_t)b * kC + chunk * 256 + il) * kQ + j0 + c];
                et[p * 4 + r][c] = smc[il] ? __expf(v - cmj) : 0.f;
            }
        }
        {
            int hr = t / 32, ic = t % 32;
#pragma unroll
            for (int p = 0; p < 16; ++p) {
                int h = p * 8 + hr;
                ctT[ic][h] = ctx[((size_t)b * kH + h) * kC + i0 + ic];
            }
        }
        __syncthreads();
#pragma unroll 8
        for (int i = 0; i < 32; ++i) {
            float4 e  = *(const float4*)&et[i][jj];
            float4 c0 = *(const float4*)&ctT[i][hh];
            float4 c1 = *(const float4*)&ctT[i][hh + 4];
            float cv[8] = {c0.x, c0.y, c0.z, c0.w, c1.x, c1.y, c1.z, c1.w};
            float ev[4] = {e.x, e.y, e.z, e.w};
#pragma unroll
            for (int u = 0; u < 8; ++u)
#pragma unroll
                for (int v = 0; v < 4; ++v)
                    acc[u][v] += cv[u] * ev[v];
        }
        __syncthreads();
    }
    const size_t M = (size_t)kB * kH * kQ;
#pragma unroll
    for (int u = 0; u < 8; ++u) {
        size_t base = (size_t)chunk * M + ((size_t)b * kH + hh + u) * kQ + j0 + jj;
        *(float4*)&Tpart[base] = make_float4(acc[u][0], acc[u][1], acc[u][2], acc[u][3]);
    }
}

// T_bf16[b,h,j] = bf16( colinv[b,j] * sum_chunk Tpart[chunk][b,h,j] )
__global__ __launch_bounds__(256) void k_Tred(const float* __restrict__ Tpart,
                                              const float* __restrict__ colinv,
                                              unsigned short* __restrict__ Tb) {
    size_t id = (size_t)blockIdx.x * 256 + threadIdx.x;   // over B*H*Q
    const size_t M = (size_t)kB * kH * kQ;
    int j = (int)(id % kQ);
    int b = (int)(id / ((size_t)kH * kQ));
    float s = 0.f;
#pragma unroll
    for (int c = 0; c < 8; ++c) s += Tpart[c * M + id];
    Tb[id] = f2bf(s * colinv[b * kQ + j]);
}

// MFMA output kernel: per block, 64 i x all 128 h; K-loop over Q in steps of 32.
// A = rownorm(S) computed on the fly (bf16); B1 = q (bf16 on the fly); B2 = T (bf16).
// c2q = A@q^T, q2c = A@T^T via mfma_f32_16x16x32_bf16, epilogue LDS-transposed
// so global writes are coalesced over i.
__global__ __launch_bounds__(256) void k_out_mfma(const float* __restrict__ S,
                                                  const float* __restrict__ q,
                                                  const unsigned short* __restrict__ Tb,
                                                  const float* __restrict__ ctx,
                                                  const int* __restrict__ qmask,
                                                  const float* __restrict__ rowmax,
                                                  const float* __restrict__ rowinv,
                                                  float* __restrict__ out) {
    int i0 = blockIdx.x * 64;
    int b  = blockIdx.y;
    __shared__ unsigned short As[64 * 40];    // [i][j] rows padded to 40 (80B)
    __shared__ unsigned short qs[128 * 40];   // [h][j]
    __shared__ unsigned short ts[128 * 40];   // [h][j]
    __shared__ int smq[256];
    __shared__ float stg[128 * 67];           // [h][i] fp32 epilogue staging
    int t = threadIdx.x;
    smq[t] = qmask[b * kQ + t];

    int rA = t >> 2, cA = (t & 3) * 8;        // A staging: 4 thr/row, 8 floats each
    float rmv = rowmax[b * kC + i0 + rA];
    float riv = rowinv[b * kC + i0 + rA];
    int rq = t >> 1, cq = (t & 1) * 16;       // B staging: 2 thr/row, 16 elems each

    int lane = t & 63, wave = t >> 6;
    int hw = wave * 32;                       // wave's h quadrant
    int kgrp = (lane >> 4) * 8;               // k-group within K=32 fragment
    int lrow = lane & 15;

    f32x4 accC[4][2];
    f32x4 accT[4][2];
#pragma unroll
    for (int mt = 0; mt < 4; ++mt)
#pragma unroll
        for (int nt = 0; nt < 2; ++nt) {
            accC[mt][nt] = (f32x4){0.f, 0.f, 0.f, 0.f};
            accT[mt][nt] = (f32x4){0.f, 0.f, 0.f, 0.f};
        }
    __syncthreads();   // smq ready

    for (int kk = 0; kk < 8; ++kk) {
        int j0 = kk * 32;
        {   // A: raw S -> masked rownorm -> bf16
            const float* src = S + ((size_t)b * kC + i0 + rA) * kQ + j0 + cA;
            float4 v0 = *(const float4*)src;
            float4 v1 = *(const float4*)(src + 4);
            float vv[8] = {v0.x, v0.y, v0.z, v0.w, v1.x, v1.y, v1.z, v1.w};
            bf16x8 p;
#pragma unroll
            for (int e = 0; e < 8; ++e) {
                float r = smq[j0 + cA + e] ? __expf(vv[e] - rmv) * riv : 0.f;
                p[e] = (short)f2bf(r);
            }
            *(bf16x8*)&As[rA * 40 + cA] = p;
        }
        {   // q fp32 -> bf16
            const float* src = q + ((size_t)b * kH + rq) * kQ + j0 + cq;
            float4 a0 = *(const float4*)src;
            float4 a1 = *(const float4*)(src + 4);
            float4 a2 = *(const float4*)(src + 8);
            float4 a3 = *(const float4*)(src + 12);
            float vv[16] = {a0.x, a0.y, a0.z, a0.w, a1.x, a1.y, a1.z, a1.w,
                            a2.x, a2.y, a2.z, a2.w, a3.x, a3.y, a3.z, a3.w};
            bf16x8 p0, p1;
#pragma unroll
            for (int e = 0; e < 8; ++e) {
                p0[e] = (short)f2bf(vv[e]);
                p1[e] = (short)f2bf(vv[8 + e]);
            }
            *(bf16x8*)&qs[rq * 40 + cq] = p0;
            *(bf16x8*)&qs[rq * 40 + cq + 8] = p1;
        }
        {   // T bf16 direct copy
            const unsigned short* src = Tb + ((size_t)b * kH + rq) * kQ + j0 + cq;
            *(bf16x8*)&ts[rq * 40 + cq]     = *(const bf16x8*)src;
            *(bf16x8*)&ts[rq * 40 + cq + 8] = *(const bf16x8*)(src + 8);
        }
        __syncthreads();
        bf16x8 af[4];
#pragma unroll
        for (int mt = 0; mt < 4; ++mt)
            af[mt] = *(const bf16x8*)&As[(mt * 16 + lrow) * 40 + kgrp];
#pragma unroll
        for (int nt = 0; nt < 2; ++nt) {
            bf16x8 bq = *(const bf16x8*)&qs[(hw + nt * 16 + lrow) * 40 + kgrp];
            bf16x8 bt = *(const bf16x8*)&ts[(hw + nt * 16 + lrow) * 40 + kgrp];
#pragma unroll
            for (int mt = 0; mt < 4; ++mt) {
                accC[mt][nt] = __builtin_amdgcn_mfma_f32_16x16x32_bf16(af[mt], bq, accC[mt][nt], 0, 0, 0);
                accT[mt][nt] = __builtin_amdgcn_mfma_f32_16x16x32_bf16(af[mt], bt, accT[mt][nt], 0, 0, 0);
            }
        }
        __syncthreads();
    }

    const size_t N = (size_t)kB * kH * kC;
    int ii = t & 63, hb = t >> 6;
    // ---- c2q: stage [h][i], then coalesced writes of out0/1/2 ----
#pragma unroll
    for (int mt = 0; mt < 4; ++mt)
#pragma unroll
        for (int nt = 0; nt < 2; ++nt)
#pragma unroll
            for (int r = 0; r < 4; ++r)
                stg[(hw + nt * 16 + lrow) * 67 + mt * 16 + (lane >> 4) * 4 + r] = accC[mt][nt][r];
    __syncthreads();
#pragma unroll 4
    for (int p = 0; p < 32; ++p) {
        int h = hb + p * 4;
        float v = stg[h * 67 + ii];
        size_t base = ((size_t)b * kH + h) * kC + i0 + ii;
        float c = ctx[base];
        out[base]         = c;
        out[N + base]     = v;
        out[2 * N + base] = c * v;
    }
    __syncthreads();
    // ---- q2c: stage, then out3 ----
#pragma unroll
    for (int mt = 0; mt < 4; ++mt)
#pragma unroll
        for (int nt = 0; nt < 2; ++nt)
#pragma unroll
            for (int r = 0; r < 4; ++r)
                stg[(hw + nt * 16 + lrow) * 67 + mt * 16 + (lane >> 4) * 4 + r] = accT[mt][nt][r];
    __syncthreads();
#pragma unroll 4
    for (int p = 0; p < 32; ++p) {
        int h = hb + p * 4;
        float v = stg[h * 67 + ii];
        size_t base = ((size_t)b * kH + h) * kC + i0 + ii;
        float c = ctx[base];
        out[3 * N + base] = c * v;
    }
}

extern "C" void kernel_launch(void* const* d_in, const int* in_sizes, int n_in,
                              void* d_out, int out_size, void* d_ws, size_t ws_size,
                              hipStream_t stream) {
    const float* ctx   = (const float*)d_in[0];
    const float* q     = (const float*)d_in[1];
    const int*   cmask = (const int*)d_in[2];
    const int*   qmask = (const int*)d_in[3];
    const float* w_c   = (const float*)d_in[4];
    const float* w_q   = (const float*)d_in[5];
    const float* w_cq  = (const float*)d_in[6];
    const float* bias  = (const float*)d_in[7];
    float* out = (float*)d_out;

    float* ws = (float*)d_ws;
    float* S            = ws;                              // B*C*Q f32
    unsigned short* Tb  = (unsigned short*)(S + (size_t)kB * kC * kQ);  // B*H*Q bf16
    float* part_c = (float*)(Tb + (size_t)kB * kH * kQ);   // B*C
    float* part_q = part_c + kB * kC;                      // B*Q
    float* rowmax = part_q + kB * kQ;                      // B*C
    float* rowinv = rowmax + kB * kC;                      // B*C
    float* colmax = rowinv + kB * kC;                      // B*Q
    float* colinv = colmax + kB * kQ;                      // B*Q
    float* pm     = colinv + kB * kQ;                      // B*kColChunks*Q
    float* ps     = pm + kB * kColChunks * kQ;             // B*kColChunks*Q
    size_t need = (size_t)((char*)(ps + kB * kColChunks * kQ) - (char*)ws);
    if (ws_size < need) return;

    // Tpart (8 * B*H*Q floats = 33.5 MB) in d_out; fully overwritten by k_out_mfma.
    float* Tpart = out;

    k_partc<<<kB * kC / 256, 256, 0, stream>>>(ctx, w_c, part_c);
    k_partq<<<kB * kQ / 256, 256, 0, stream>>>(q, w_q, part_q);
    k_S<<<dim3(kC / 32, kQ / 64, kB), 256, 0, stream>>>(ctx, q, w_cq, part_c, part_q, bias, S);
    k_rowstats<<<kB * kC / 4, 256, 0, stream>>>(S, qmask, rowmax, rowinv);
    k_colpart<<<dim3(kColChunks, kB), 256, 0, stream>>>(S, cmask, pm, ps);
    k_colcombine<<<kB * kQ / 256, 256, 0, stream>>>(pm, ps, colmax, colinv);
    k_T2<<<dim3(8, kQ / 64, kB), 256, 0, stream>>>(S, ctx, cmask, colmax, Tpart);
    k_Tred<<<kB * kH * kQ / 256, 256, 0, stream>>>(Tpart, colinv, Tb);
    k_out_mfma<<<dim3(kC / 64, kB), 256, 0, stream>>>(S, q, Tb, ctx, qmask, rowmax, rowinv, out);
}

// Round 5
// 227.008 us; speedup vs baseline: 4.2696x; 1.2821x over previous
//
#include <hip/hip_runtime.h>
#include <hip/hip_bf16.h>
#include <math.h>

// QANet Context-Query attention. B=32 H=128 C=2048 Q=256.
// R4: k_S -> bf16 MFMA. Pre-transpose kernels k_trc/k_trq emit K-contiguous
//     bf16 operands ctxW[b,i,h] (= ctx*w_cq) and qT[b,j,h] into d_out scratch
//     (upper half; Tpart keeps lower 33.5MB; k_out_mfma overwrites all of
//     d_out at the end). k_S_mfma = 128x128 tile, 4 waves, K=128 in 4 steps.

constexpr int kB = 32, kH = 128, kC = 2048, kQ = 256;
constexpr int kColChunks = 32;
constexpr float kNEG = -1e30f;

typedef short bf16x8 __attribute__((ext_vector_type(8)));
typedef float f32x4 __attribute__((ext_vector_type(4)));

static __device__ __forceinline__ unsigned short f2bf(float f) {
    __hip_bfloat16 h = __float2bfloat16(f);
    return __builtin_bit_cast(unsigned short, h);
}

__global__ __launch_bounds__(256) void k_partc(const float* __restrict__ ctx,
                                               const float* __restrict__ w_c,
                                               float* __restrict__ part_c) {
    int id = blockIdx.x * 256 + threadIdx.x;   // over B*C
    int b = id / kC, i = id % kC;
    float acc = 0.f;
#pragma unroll 8
    for (int h = 0; h < kH; ++h)
        acc += ctx[((size_t)b * kH + h) * kC + i] * w_c[h];
    part_c[id] = acc;
}

__global__ __launch_bounds__(256) void k_partq(const float* __restrict__ q,
                                               const float* __restrict__ w_q,
                                               float* __restrict__ part_q) {
    int id = blockIdx.x * 256 + threadIdx.x;   // over B*Q
    int b = id / kQ, j = id % kQ;
    float acc = 0.f;
#pragma unroll 8
    for (int h = 0; h < kH; ++h)
        acc += q[((size_t)b * kH + h) * kQ + j] * w_q[h];
    part_q[id] = acc;
}

// Transpose ctx [b,h,i] -> ctxW bf16 [b,i,h], scaled by w_cq[h].
// Block: 64 i x 128 h. Packed u32 LDS writes (2 h per thread).
__global__ __launch_bounds__(256) void k_trc(const float* __restrict__ ctx,
                                             const float* __restrict__ w_cq,
                                             unsigned short* __restrict__ ctxW) {
    int i0 = blockIdx.x * 64, b = blockIdx.y;
    __shared__ unsigned short tile[64 * 136];
    int t = threadIdx.x;
    int il = t & 63;
    int hb = (t >> 6) * 2;
#pragma unroll
    for (int r = 0; r < 16; ++r) {
        int h = r * 8 + hb;
        float v0 = ctx[((size_t)b * kH + h) * kC + i0 + il] * w_cq[h];
        float v1 = ctx[((size_t)b * kH + h + 1) * kC + i0 + il] * w_cq[h + 1];
        unsigned int pk = (unsigned int)f2bf(v0) | ((unsigned int)f2bf(v1) << 16);
        *(unsigned int*)&tile[il * 136 + h] = pk;
    }
    __syncthreads();
#pragma unroll
    for (int r = 0; r < 4; ++r) {
        int idx = r * 256 + t;
        int i = idx >> 4, hc = (idx & 15) * 8;
        *(bf16x8*)&ctxW[((size_t)b * kC + i0 + i) * kH + hc] =
            *(const bf16x8*)&tile[i * 136 + hc];
    }
}

// Transpose q [b,h,j] -> qT bf16 [b,j,h]. Block: 64 j x 128 h.
__global__ __launch_bounds__(256) void k_trq(const float* __restrict__ q,
                                             unsigned short* __restrict__ qT) {
    int j0 = blockIdx.x * 64, b = blockIdx.y;
    __shared__ unsigned short tile[64 * 136];
    int t = threadIdx.x;
    int jl = t & 63;
    int hb = (t >> 6) * 2;
#pragma unroll
    for (int r = 0; r < 16; ++r) {
        int h = r * 8 + hb;
        float v0 = q[((size_t)b * kH + h) * kQ + j0 + jl];
        float v1 = q[((size_t)b * kH + h + 1) * kQ + j0 + jl];
        unsigned int pk = (unsigned int)f2bf(v0) | ((unsigned int)f2bf(v1) << 16);
        *(unsigned int*)&tile[jl * 136 + h] = pk;
    }
    __syncthreads();
#pragma unroll
    for (int r = 0; r < 4; ++r) {
        int idx = r * 256 + t;
        int j = idx >> 4, hc = (idx & 15) * 8;
        *(bf16x8*)&qT[((size_t)b * kQ + j0 + j) * kH + hc] =
            *(const bf16x8*)&tile[j * 136 + hc];
    }
}

// S via MFMA: S[b,i,j] = ctxW[b,i,:] . qT[b,j,:] + part_c + part_q + bias.
// Block 128i x 128j, 4 waves (2x2 of 64x64), K=128 in 4 steps of 32.
__global__ __launch_bounds__(256) void k_S_mfma(const unsigned short* __restrict__ ctxW,
                                                const unsigned short* __restrict__ qT,
                                                const float* __restrict__ part_c,
                                                const float* __restrict__ part_q,
                                                const float* __restrict__ bias,
                                                float* __restrict__ S) {
    int i0 = blockIdx.x * 128, j0 = blockIdx.y * 128, b = blockIdx.z;
    __shared__ unsigned short As[128 * 40];
    __shared__ unsigned short Bs[128 * 40];
    int t = threadIdx.x;
    int lane = t & 63, wave = t >> 6;
    int wm = wave >> 1, wn = wave & 1;
    int lrow = lane & 15, kgrp = (lane >> 4) * 8;

    f32x4 acc[4][4];
#pragma unroll
    for (int mt = 0; mt < 4; ++mt)
#pragma unroll
        for (int nt = 0; nt < 4; ++nt)
            acc[mt][nt] = (f32x4){0.f, 0.f, 0.f, 0.f};

    for (int kk = 0; kk < 4; ++kk) {
        int h0 = kk * 32;
#pragma unroll
        for (int r = 0; r < 2; ++r) {
            int idx = r * 256 + t;
            int i = idx >> 2, hc = (idx & 3) * 8;
            *(bf16x8*)&As[i * 40 + hc] =
                *(const bf16x8*)&ctxW[((size_t)b * kC + i0 + i) * kH + h0 + hc];
            *(bf16x8*)&Bs[i * 40 + hc] =
                *(const bf16x8*)&qT[((size_t)b * kQ + j0 + i) * kH + h0 + hc];
        }
        __syncthreads();
        bf16x8 af[4], bf[4];
#pragma unroll
        for (int mt = 0; mt < 4; ++mt)
            af[mt] = *(const bf16x8*)&As[(wm * 64 + mt * 16 + lrow) * 40 + kgrp];
#pragma unroll
        for (int nt = 0; nt < 4; ++nt)
            bf[nt] = *(const bf16x8*)&Bs[(wn * 64 + nt * 16 + lrow) * 40 + kgrp];
#pragma unroll
        for (int nt = 0; nt < 4; ++nt)
#pragma unroll
            for (int mt = 0; mt < 4; ++mt)
                acc[mt][nt] = __builtin_amdgcn_mfma_f32_16x16x32_bf16(af[mt], bf[nt], acc[mt][nt], 0, 0, 0);
        __syncthreads();
    }

    float bs = bias[0];
    float pq[4];
#pragma unroll
    for (int nt = 0; nt < 4; ++nt)
        pq[nt] = part_q[b * kQ + j0 + wn * 64 + nt * 16 + lrow];
#pragma unroll
    for (int mt = 0; mt < 4; ++mt)
#pragma unroll
        for (int r = 0; r < 4; ++r) {
            int i = i0 + wm * 64 + mt * 16 + (lane >> 4) * 4 + r;
            float pc = part_c[b * kC + i] + bs;
            float* dst = S + ((size_t)b * kC + i) * kQ + j0 + wn * 64 + lrow;
#pragma unroll
            for (int nt = 0; nt < 4; ++nt)
                dst[nt * 16] = acc[mt][nt][r] + pc + pq[nt];
        }
}

// One wave per (b,i) row: max + sum of exp over Q=256 (4 elems/lane).
__global__ __launch_bounds__(256) void k_rowstats(const float* __restrict__ S,
                                                  const int* __restrict__ qmask,
                                                  float* __restrict__ rowmax,
                                                  float* __restrict__ rowinv) {
    int gtid = blockIdx.x * 256 + threadIdx.x;
    int wid = gtid / 64;          // row id over B*C
    int lane = threadIdx.x % 64;
    int b = wid / kC;
    const float* row = S + (size_t)wid * kQ;
    const int* qm = qmask + b * kQ;
    float v[4];
    float m = kNEG;
#pragma unroll
    for (int k = 0; k < 4; ++k) {
        int j = lane + k * 64;
        v[k] = qm[j] ? row[j] : kNEG;
        m = fmaxf(m, v[k]);
    }
    for (int off = 32; off; off >>= 1) m = fmaxf(m, __shfl_xor(m, off));
    float s = 0.f;
#pragma unroll
    for (int k = 0; k < 4; ++k) s += (v[k] > -1e29f) ? __expf(v[k] - m) : 0.f;
    for (int off = 32; off; off >>= 1) s += __shfl_xor(s, off);
    if (lane == 0) { rowmax[wid] = m; rowinv[wid] = 1.f / s; }
}

// Column-softmax partial stats: kColChunks chunks; 256 thr = Q.
__global__ __launch_bounds__(256) void k_colpart(const float* __restrict__ S,
                                                 const int* __restrict__ cmask,
                                                 float* __restrict__ pm,
                                                 float* __restrict__ ps) {
    int chunk = blockIdx.x, b = blockIdx.y;
    int j = threadIdx.x;
    const int* cm = cmask + b * kC;
    float m = kNEG, s = 0.f;
    int ibeg = chunk * (kC / kColChunks);
    for (int i = ibeg; i < ibeg + kC / kColChunks; ++i) {
        if (!cm[i]) continue;
        float v = S[((size_t)b * kC + i) * kQ + j];
        if (v > m) { s = s * __expf(m - v) + 1.f; m = v; }
        else       { s += __expf(v - m); }
    }
    pm[(b * kColChunks + chunk) * kQ + j] = m;
    ps[(b * kColChunks + chunk) * kQ + j] = s;
}

__global__ __launch_bounds__(256) void k_colcombine(const float* __restrict__ pm,
                                                    const float* __restrict__ ps,
                                                    float* __restrict__ colmax,
                                                    float* __restrict__ colinv) {
    int id = blockIdx.x * 256 + threadIdx.x;   // over B*Q
    int b = id / kQ, j = id % kQ;
    float m = kNEG;
#pragma unroll
    for (int c = 0; c < kColChunks; ++c) m = fmaxf(m, pm[(b * kColChunks + c) * kQ + j]);
    float s = 0.f;
#pragma unroll
    for (int c = 0; c < kColChunks; ++c) {
        float pmv = pm[(b * kColChunks + c) * kQ + j];
        float psv = ps[(b * kColChunks + c) * kQ + j];
        if (pmv > -1e29f) s += psv * __expf(pmv - m);
    }
    colmax[id] = m;
    colinv[id] = 1.f / s;
}

// Tpart[chunk][b][h][j] = sum_{i in chunk} cmask[i]*exp(S[i,j]-colmax[j])*ctx[h,i]
__global__ __launch_bounds__(256) void k_T2(const float* __restrict__ S,
                                            const float* __restrict__ ctx,
                                            const int* __restrict__ cmask,
                                            const float* __restrict__ colmax,
                                            float* __restrict__ Tpart) {
    int chunk = blockIdx.x, jt = blockIdx.y, b = blockIdx.z;
    int j0 = jt * 64;
    __shared__ float et[32][68];
    __shared__ float ctT[32][132];
    __shared__ int   smc[256];
    int t = threadIdx.x;
    int jj = (t % 16) * 4;
    int hh = (t / 16) * 8;
    float cmj = colmax[b * kQ + j0 + (t % 64)];
    smc[t] = cmask[b * kC + chunk * 256 + t];
    __syncthreads();
    float acc[8][4] = {};
    for (int it = 0; it < 8; ++it) {
        int i0 = chunk * 256 + it * 32;
        {
            int r = t / 64, c = t % 64;
#pragma unroll
            for (int p = 0; p < 8; ++p) {
                int il = it * 32 + p * 4 + r;
                float v = S[((size_t)b * kC + chunk * 256 + il) * kQ + j0 + c];
                et[p * 4 + r][c] = smc[il] ? __expf(v - cmj) : 0.f;
            }
        }
        {
            int hr = t / 32, ic = t % 32;
#pragma unroll
            for (int p = 0; p < 16; ++p) {
                int h = p * 8 + hr;
                ctT[ic][h] = ctx[((size_t)b * kH + h) * kC + i0 + ic];
            }
        }
        __syncthreads();
#pragma unroll 8
        for (int i = 0; i < 32; ++i) {
            float4 e  = *(const float4*)&et[i][jj];
            float4 c0 = *(const float4*)&ctT[i][hh];
            float4 c1 = *(const float4*)&ctT[i][hh + 4];
            float cv[8] = {c0.x, c0.y, c0.z, c0.w, c1.x, c1.y, c1.z, c1.w};
            float ev[4] = {e.x, e.y, e.z, e.w};
#pragma unroll
            for (int u = 0; u < 8; ++u)
#pragma unroll
                for (int v = 0; v < 4; ++v)
                    acc[u][v] += cv[u] * ev[v];
        }
        __syncthreads();
    }
    const size_t M = (size_t)kB * kH * kQ;
#pragma unroll
    for (int u = 0; u < 8; ++u) {
        size_t base = (size_t)chunk * M + ((size_t)b * kH + hh + u) * kQ + j0 + jj;
        *(float4*)&Tpart[base] = make_float4(acc[u][0], acc[u][1], acc[u][2], acc[u][3]);
    }
}

// T_bf16[b,h,j] = bf16( colinv[b,j] * sum_chunk Tpart[chunk][b,h,j] )
__global__ __launch_bounds__(256) void k_Tred(const float* __restrict__ Tpart,
                                              const float* __restrict__ colinv,
                                              unsigned short* __restrict__ Tb) {
    size_t id = (size_t)blockIdx.x * 256 + threadIdx.x;   // over B*H*Q
    const size_t M = (size_t)kB * kH * kQ;
    int j = (int)(id % kQ);
    int b = (int)(id / ((size_t)kH * kQ));
    float s = 0.f;
#pragma unroll
    for (int c = 0; c < 8; ++c) s += Tpart[c * M + id];
    Tb[id] = f2bf(s * colinv[b * kQ + j]);
}

// MFMA output kernel: per block, 64 i x all 128 h; K-loop over Q in steps of 32.
__global__ __launch_bounds__(256) void k_out_mfma(const float* __restrict__ S,
                                                  const float* __restrict__ q,
                                                  const unsigned short* __restrict__ Tb,
                                                  const float* __restrict__ ctx,
                                                  const int* __restrict__ qmask,
                                                  const float* __restrict__ rowmax,
                                                  const float* __restrict__ rowinv,
                                                  float* __restrict__ out) {
    int i0 = blockIdx.x * 64;
    int b  = blockIdx.y;
    __shared__ unsigned short As[64 * 40];    // [i][j] rows padded to 40 (80B)
    __shared__ unsigned short qs[128 * 40];   // [h][j]
    __shared__ unsigned short ts[128 * 40];   // [h][j]
    __shared__ int smq[256];
    __shared__ float stg[128 * 67];           // [h][i] fp32 epilogue staging
    int t = threadIdx.x;
    smq[t] = qmask[b * kQ + t];

    int rA = t >> 2, cA = (t & 3) * 8;        // A staging: 4 thr/row, 8 floats each
    float rmv = rowmax[b * kC + i0 + rA];
    float riv = rowinv[b * kC + i0 + rA];
    int rq = t >> 1, cq = (t & 1) * 16;       // B staging: 2 thr/row, 16 elems each

    int lane = t & 63, wave = t >> 6;
    int hw = wave * 32;                       // wave's h quadrant
    int kgrp = (lane >> 4) * 8;               // k-group within K=32 fragment
    int lrow = lane & 15;

    f32x4 accC[4][2];
    f32x4 accT[4][2];
#pragma unroll
    for (int mt = 0; mt < 4; ++mt)
#pragma unroll
        for (int nt = 0; nt < 2; ++nt) {
            accC[mt][nt] = (f32x4){0.f, 0.f, 0.f, 0.f};
            accT[mt][nt] = (f32x4){0.f, 0.f, 0.f, 0.f};
        }
    __syncthreads();   // smq ready

    for (int kk = 0; kk < 8; ++kk) {
        int j0 = kk * 32;
        {   // A: raw S -> masked rownorm -> bf16
            const float* src = S + ((size_t)b * kC + i0 + rA) * kQ + j0 + cA;
            float4 v0 = *(const float4*)src;
            float4 v1 = *(const float4*)(src + 4);
            float vv[8] = {v0.x, v0.y, v0.z, v0.w, v1.x, v1.y, v1.z, v1.w};
            bf16x8 p;
#pragma unroll
            for (int e = 0; e < 8; ++e) {
                float r = smq[j0 + cA + e] ? __expf(vv[e] - rmv) * riv : 0.f;
                p[e] = (short)f2bf(r);
            }
            *(bf16x8*)&As[rA * 40 + cA] = p;
        }
        {   // q fp32 -> bf16
            const float* src = q + ((size_t)b * kH + rq) * kQ + j0 + cq;
            float4 a0 = *(const float4*)src;
            float4 a1 = *(const float4*)(src + 4);
            float4 a2 = *(const float4*)(src + 8);
            float4 a3 = *(const float4*)(src + 12);
            float vv[16] = {a0.x, a0.y, a0.z, a0.w, a1.x, a1.y, a1.z, a1.w,
                            a2.x, a2.y, a2.z, a2.w, a3.x, a3.y, a3.z, a3.w};
            bf16x8 p0, p1;
#pragma unroll
            for (int e = 0; e < 8; ++e) {
                p0[e] = (short)f2bf(vv[e]);
                p1[e] = (short)f2bf(vv[8 + e]);
            }
            *(bf16x8*)&qs[rq * 40 + cq] = p0;
            *(bf16x8*)&qs[rq * 40 + cq + 8] = p1;
        }
        {   // T bf16 direct copy
            const unsigned short* src = Tb + ((size_t)b * kH + rq) * kQ + j0 + cq;
            *(bf16x8*)&ts[rq * 40 + cq]     = *(const bf16x8*)src;
            *(bf16x8*)&ts[rq * 40 + cq + 8] = *(const bf16x8*)(src + 8);
        }
        __syncthreads();
        bf16x8 af[4];
#pragma unroll
        for (int mt = 0; mt < 4; ++mt)
            af[mt] = *(const bf16x8*)&As[(mt * 16 + lrow) * 40 + kgrp];
#pragma unroll
        for (int nt = 0; nt < 2; ++nt) {
            bf16x8 bq = *(const bf16x8*)&qs[(hw + nt * 16 + lrow) * 40 + kgrp];
            bf16x8 bt = *(const bf16x8*)&ts[(hw + nt * 16 + lrow) * 40 + kgrp];
#pragma unroll
            for (int mt = 0; mt < 4; ++mt) {
                accC[mt][nt] = __builtin_amdgcn_mfma_f32_16x16x32_bf16(af[mt], bq, accC[mt][nt], 0, 0, 0);
                accT[mt][nt] = __builtin_amdgcn_mfma_f32_16x16x32_bf16(af[mt], bt, accT[mt][nt], 0, 0, 0);
            }
        }
        __syncthreads();
    }

    const size_t N = (size_t)kB * kH * kC;
    int ii = t & 63, hb = t >> 6;
    // ---- c2q: stage [h][i], then coalesced writes of out0/1/2 ----
#pragma unroll
    for (int mt = 0; mt < 4; ++mt)
#pragma unroll
        for (int nt = 0; nt < 2; ++nt)
#pragma unroll
            for (int r = 0; r < 4; ++r)
                stg[(hw + nt * 16 + lrow) * 67 + mt * 16 + (lane >> 4) * 4 + r] = accC[mt][nt][r];
    __syncthreads();
#pragma unroll 4
    for (int p = 0; p < 32; ++p) {
        int h = hb + p * 4;
        float v = stg[h * 67 + ii];
        size_t base = ((size_t)b * kH + h) * kC + i0 + ii;
        float c = ctx[base];
        out[base]         = c;
        out[N + base]     = v;
        out[2 * N + base] = c * v;
    }
    __syncthreads();
    // ---- q2c: stage, then out3 ----
#pragma unroll
    for (int mt = 0; mt < 4; ++mt)
#pragma unroll
        for (int nt = 0; nt < 2; ++nt)
#pragma unroll
            for (int r = 0; r < 4; ++r)
                stg[(hw + nt * 16 + lrow) * 67 + mt * 16 + (lane >> 4) * 4 + r] = accT[mt][nt][r];
    __syncthreads();
#pragma unroll 4
    for (int p = 0; p < 32; ++p) {
        int h = hb + p * 4;
        float v = stg[h * 67 + ii];
        size_t base = ((size_t)b * kH + h) * kC + i0 + ii;
        float c = ctx[base];
        out[3 * N + base] = c * v;
    }
}

extern "C" void kernel_launch(void* const* d_in, const int* in_sizes, int n_in,
                              void* d_out, int out_size, void* d_ws, size_t ws_size,
                              hipStream_t stream) {
    const float* ctx   = (const float*)d_in[0];
    const float* q     = (const float*)d_in[1];
    const int*   cmask = (const int*)d_in[2];
    const int*   qmask = (const int*)d_in[3];
    const float* w_c   = (const float*)d_in[4];
    const float* w_q   = (const float*)d_in[5];
    const float* w_cq  = (const float*)d_in[6];
    const float* bias  = (const float*)d_in[7];
    float* out = (float*)d_out;

    float* ws = (float*)d_ws;
    float* S            = ws;                              // B*C*Q f32
    unsigned short* Tb  = (unsigned short*)(S + (size_t)kB * kC * kQ);  // B*H*Q bf16
    float* part_c = (float*)(Tb + (size_t)kB * kH * kQ);   // B*C
    float* part_q = part_c + kB * kC;                      // B*Q
    float* rowmax = part_q + kB * kQ;                      // B*C
    float* rowinv = rowmax + kB * kC;                      // B*C
    float* colmax = rowinv + kB * kC;                      // B*Q
    float* colinv = colmax + kB * kQ;                      // B*Q
    float* pm     = colinv + kB * kQ;                      // B*kColChunks*Q
    float* ps     = pm + kB * kColChunks * kQ;             // B*kColChunks*Q
    size_t need = (size_t)((char*)(ps + kB * kColChunks * kQ) - (char*)ws);
    if (ws_size < need) return;

    // d_out scratch map (134 MB total; k_out_mfma overwrites everything):
    //   [0, 33.5MB)   Tpart  (8 * B*H*Q f32)
    //   [67, 83.8MB)  ctxW   (B*C*H bf16)
    //   [83.8, 86MB)  qT     (B*Q*H bf16)
    const size_t N = (size_t)kB * kH * kC;
    float* Tpart = out;
    unsigned short* ctxW = (unsigned short*)(out + 2 * N);
    unsigned short* qT   = ctxW + (size_t)kB * kC * kH;

    k_trc<<<dim3(kC / 64, kB), 256, 0, stream>>>(ctx, w_cq, ctxW);
    k_trq<<<dim3(kQ / 64, kB), 256, 0, stream>>>(q, qT);
    k_partc<<<kB * kC / 256, 256, 0, stream>>>(ctx, w_c, part_c);
    k_partq<<<kB * kQ / 256, 256, 0, stream>>>(q, w_q, part_q);
    k_S_mfma<<<dim3(kC / 128, kQ / 128, kB), 256, 0, stream>>>(ctxW, qT, part_c, part_q, bias, S);
    k_rowstats<<<kB * kC / 4, 256, 0, stream>>>(S, qmask, rowmax, rowinv);
    k_colpart<<<dim3(kColChunks, kB), 256, 0, stream>>>(S, cmask, pm, ps);
    k_colcombine<<<kB * kQ / 256, 256, 0, stream>>>(pm, ps, colmax, colinv);
    k_T2<<<dim3(8, kQ / 64, kB), 256, 0, stream>>>(S, ctx, cmask, colmax, Tpart);
    k_Tred<<<kB * kH * kQ / 256, 256, 0, stream>>>(Tpart, colinv, Tb);
    k_out_mfma<<<dim3(kC / 64, kB), 256, 0, stream>>>(S, q, Tb, ctx, qmask, rowmax, rowinv, out);
}